// Round 1
// baseline (40200.467 us; speedup 1.0000x reference)
//
#include <hip/hip_runtime.h>
#include <stdint.h>

// AutoRegressiveLSTM: B=128, T=1024, I=128, H=1024, O=128. 4H=4096, K=I+H (+O fused)
#define Tn 1024
#define In 128

typedef __attribute__((ext_vector_type(8))) short short8;
typedef __attribute__((ext_vector_type(4))) float f32x4;

// ---- workspace layout (bytes) ----
#define WS_WFRAG  0ull                         // 32u*8nt*40kt*64lane*16B = 10,485,760
#define WS_WOUT   (WS_WFRAG + 10485760ull)     // 8u*32kt*1024B = 262,144
#define WS_Z0     (WS_WOUT + 262144ull)        // 8m*4kt*1024B = 32,768
#define WS_HBUF   (WS_Z0 + 32768ull)           // 2buf*8m*32kt*1024B = 524,288
#define WS_BIAS   (WS_HBUF + 524288ull)        // 4096*4
#define WS_CNT    (WS_BIAS + 16384ull)         // 1024*8*4
// total ~11.35 MB

__device__ __forceinline__ unsigned short f2bf(float f) {
  unsigned u = __builtin_bit_cast(unsigned, f);
  return (unsigned short)((u + 0x7FFFu + ((u >> 16) & 1u)) >> 16);  // RNE
}
__device__ __forceinline__ float fast_sig(float v) {
  float e = __builtin_amdgcn_exp2f(-1.44269504089f * v);
  return __builtin_amdgcn_rcpf(1.0f + e);
}
__device__ __forceinline__ float fast_tanh(float v) {
  float a = fabsf(v);
  float e = __builtin_amdgcn_exp2f(-2.88539008178f * a);
  float r = (1.0f - e) * __builtin_amdgcn_rcpf(1.0f + e);
  return copysignf(r, v);
}

// ---------------------------------------------------------------------------
// K1: fused weights -> bf16 B-fragments.
// wfrag[u][nt][kt][lane][8]: B[k][col] for rows n(r)=g*1024+u*32+(r&31), r=nt*16+col.
//   kt 0..31  : W_comb_h[n][k] = W_hh[n][k] + sum_o W_ih[n][128+o]*W_out[o][k]
//   kt 32..35 : W_ih[n][k]           (x part)
//   kt 36..39 : W_ih[n][128+o]       (z0 correction part, used only at t=0)
// ---------------------------------------------------------------------------
__global__ void k_wfrag(const float* __restrict__ Wih, const float* __restrict__ Whh,
                        const float* __restrict__ Wout, char* __restrict__ ws) {
  const int u = blockIdx.x, nt = blockIdx.y, kt = blockIdx.z;
  const int lane = threadIdx.x;
  const int col = lane & 15, quad = lane >> 4;
  const int r = nt * 16 + col;
  const int g = r >> 5, jj = r & 31;
  const int n = g * 1024 + u * 32 + jj;
  float v[8];
  if (kt < 32) {
    const int k = kt * 32 + quad * 8;
    #pragma unroll
    for (int e = 0; e < 8; e++) v[e] = Whh[(size_t)n * 1024 + k + e];
    const float* wo = Wih + (size_t)n * 256 + 128;
    for (int o = 0; o < 128; o++) {
      const float wv = wo[o];
      const float* wr = Wout + (size_t)o * 1024 + k;
      #pragma unroll
      for (int e = 0; e < 8; e++) v[e] = fmaf(wv, wr[e], v[e]);
    }
  } else if (kt < 36) {
    const int k = (kt - 32) * 32 + quad * 8;
    #pragma unroll
    for (int e = 0; e < 8; e++) v[e] = Wih[(size_t)n * 256 + k + e];
  } else {
    const int o = (kt - 36) * 32 + quad * 8;
    #pragma unroll
    for (int e = 0; e < 8; e++) v[e] = Wih[(size_t)n * 256 + 128 + o + e];
  }
  short8 pk;
  #pragma unroll
  for (int e = 0; e < 8; e++) pk[e] = (short)f2bf(v[e]);
  *(short8*)(ws + WS_WFRAG + ((size_t)((u * 8 + nt) * 40 + kt) * 64 + lane) * 16) = pk;
}

// ---------------------------------------------------------------------------
// K2: misc setup (woutfrag, hn->frag into hbuf[1], z0 frag, bias2, flag zero)
// ---------------------------------------------------------------------------
__global__ void k_misc(const float* __restrict__ Wout, const float* __restrict__ hn,
                       const float* __restrict__ out_t, const float* __restrict__ bout,
                       const float* __restrict__ bih, const float* __restrict__ bhh,
                       const float* __restrict__ Wih, char* __restrict__ ws) {
  const int blk = blockIdx.x, lane = threadIdx.x;
  const int col = lane & 15, quad = lane >> 4;
  if (blk < 256) {                       // woutfrag[u][kt][lane][8] = Wout[o][j]
    const int u = blk >> 5, kt = blk & 31;
    const int o = u * 16 + col, j0 = kt * 32 + quad * 8;
    short8 pk;
    #pragma unroll
    for (int e = 0; e < 8; e++) pk[e] = (short)f2bf(Wout[(size_t)o * 1024 + j0 + e]);
    *(short8*)(ws + WS_WOUT + ((size_t)(u * 32 + kt) * 64 + lane) * 16) = pk;
  } else if (blk < 512) {                // hn -> A-frag layout into hbuf[1]
    const int t2 = blk - 256;
    const int mm = t2 >> 5, kt = t2 & 31;
    const int b = mm * 16 + col, j0 = kt * 32 + quad * 8;
    short8 pk;
    #pragma unroll
    for (int e = 0; e < 8; e++) pk[e] = (short)f2bf(hn[(size_t)b * 1024 + j0 + e]);
    *(short8*)(ws + WS_HBUF + ((size_t)((8 + mm) * 32 + kt) * 64 + lane) * 16) = pk;
  } else if (blk < 544) {                // z0 = output_t - b_out - hn@Wout^T (A-frag bf16)
    const int t2 = blk - 512;
    const int mm = t2 >> 2, kz = t2 & 3;
    const int b = mm * 16 + col;
    const int o0 = kz * 32 + quad * 8;
    float acc[8];
    #pragma unroll
    for (int e = 0; e < 8; e++) acc[e] = out_t[(size_t)b * 128 + o0 + e] - bout[o0 + e];
    for (int j = 0; j < 1024; j += 4) {
      const f32x4 h4 = *(const f32x4*)(hn + (size_t)b * 1024 + j);
      #pragma unroll
      for (int e = 0; e < 8; e++) {
        const f32x4 w4 = *(const f32x4*)(Wout + (size_t)(o0 + e) * 1024 + j);
        acc[e] -= h4[0] * w4[0] + h4[1] * w4[1] + h4[2] * w4[2] + h4[3] * w4[3];
      }
    }
    short8 pk;
    #pragma unroll
    for (int e = 0; e < 8; e++) pk[e] = (short)f2bf(acc[e]);
    *(short8*)(ws + WS_Z0 + ((size_t)(mm * 4 + kz) * 64 + lane) * 16) = pk;
  } else if (blk < 608) {                // bias2[n] = b_ih + b_hh + W_ihO @ b_out
    const int n = (blk - 544) * 64 + lane;
    float v = bih[n] + bhh[n];
    const float* wo = Wih + (size_t)n * 256 + 128;
    for (int o = 0; o < 128; o++) v = fmaf(wo[o], bout[o], v);
    ((float*)(ws + WS_BIAS))[n] = v;
  } else {                               // zero flag counters (8192 ints)
    int* c = (int*)(ws + WS_CNT);
    const int base = ((blk - 608) * 64 + lane) * 16;
    #pragma unroll
    for (int k = 0; k < 16; k++) c[base + k] = 0;
  }
}

// ---------------------------------------------------------------------------
// Main persistent kernel: 256 WGs x 512 thr. WG wg: m = wg&7 (batch group of 16),
// u = wg>>3 (units j in [32u,32u+32), i.e. gate rows {g*1024+32u+jj}).
// Flag-based producer/consumer sync within each 32-WG batch group.
// ---------------------------------------------------------------------------
__launch_bounds__(512, 2)
__global__ void k_main(const float* __restrict__ x, const int* __restrict__ seq,
                       const float* __restrict__ cn, const float* __restrict__ b_out,
                       float* __restrict__ out, char* __restrict__ ws) {
  __shared__ short8 a_lds[40 * 64];        // A fragments: 32 h + 4 x + 4 z0 (40 KB)
  __shared__ float  gates_lds[128 * 20];   // [row r][batch b], stride 20 (aligned+pad)
  __shared__ short8 htile[64];             // new h tile (16b x 32j) in frag order
  __shared__ float  ysred[8 * 16 * 20];    // ys split-K partials [q][o][b]
  __shared__ float  bias_lds[128];
  __shared__ int    seq_lds[16];

  const int tid  = threadIdx.x;
  const int lane = tid & 63;
  const int w    = tid >> 6;               // wave id 0..7 (= gate N-tile)
  const int wg   = blockIdx.x;
  const int m    = wg & 7, u = wg >> 3;

  const char* wfrag = ws + WS_WFRAG;
  const char* woutf = ws + WS_WOUT;
  char* hbuf  = ws + WS_HBUF;
  const float* bias2 = (const float*)(ws + WS_BIAS);
  int* cnt = (int*)(ws + WS_CNT);

  // persistent weight B-fragments in VGPRs: 40 x 16B = 160 VGPRs
  short8 bfr[40];
  {
    const char* base = wfrag + ((size_t)(u * 8 + w) * 40 * 64) * 16 + (size_t)lane * 16;
    #pragma unroll
    for (int kt = 0; kt < 40; kt++) bfr[kt] = *(const short8*)(base + (size_t)kt * 1024);
  }
  if (tid < 16) seq_lds[tid] = seq[m * 16 + tid];
  if (tid < 128) {
    const int g = tid >> 5, jj = tid & 31;
    bias_lds[tid] = bias2[g * 1024 + u * 32 + jj];
  }
  const int b_loc  = tid & 15;   // batch within group
  const int jj_loc = tid >> 4;   // unit within WG (0..31)
  float c_reg = cn[(size_t)(m * 16 + b_loc) * 1024 + u * 32 + jj_loc];
  __syncthreads();

  #pragma unroll 1
  for (int tt = 0; tt <= Tn; tt++) {
    // ---- wait for all 32 producers of h_{tt-1} in this batch group ----
    if (tt >= 1) {
      if (tid == 0) {
        while (__hip_atomic_load(&cnt[(tt - 1) * 8 + m], __ATOMIC_RELAXED,
                                 __HIP_MEMORY_SCOPE_AGENT) < 32)
          __builtin_amdgcn_s_sleep(2);
      }
      __syncthreads();
      __threadfence();   // acquire: invalidate L1 so fresh h/x/wout are read
    }
    // ---- stage h_{tt-1} fragments (32 KB) into LDS (tt==0: hn frags in hbuf[1]) ----
    {
      const char* src = hbuf + (size_t)((((tt + 1) & 1) * 8) + m) * 32768;
      #pragma unroll
      for (int s = 0; s < 4; s++) {
        const int idx = s * 512 + tid;   // 2048 x 16B, fully coalesced
        a_lds[idx] = *(const short8*)(src + (size_t)idx * 16);
      }
    }
    // ---- stage x_t (masked, bf16, frag layout) ----
    if (tt < Tn && tid < 256) {
      const int kt4 = tid >> 6, ln = tid & 63;
      const int b = ln & 15, quad = ln >> 4;
      const int i0 = kt4 * 32 + quad * 8;
      const float* xp = x + ((size_t)(m * 16 + b) * Tn + tt) * In + i0;
      const float mk = (tt < seq_lds[b]) ? 1.0f : 0.0f;
      const f32x4 x0 = *(const f32x4*)xp;
      const f32x4 x1 = *(const f32x4*)(xp + 4);
      short8 pk;
      pk[0] = (short)f2bf(x0[0] * mk); pk[1] = (short)f2bf(x0[1] * mk);
      pk[2] = (short)f2bf(x0[2] * mk); pk[3] = (short)f2bf(x0[3] * mk);
      pk[4] = (short)f2bf(x1[0] * mk); pk[5] = (short)f2bf(x1[1] * mk);
      pk[6] = (short)f2bf(x1[2] * mk); pk[7] = (short)f2bf(x1[3] * mk);
      a_lds[(32 + kt4) * 64 + ln] = pk;
    }
    // ---- stage z0 correction frags (t=0 only) ----
    if (tt == 0 && tid < 256) {
      const int kz = tid >> 6, ln = tid & 63;
      a_lds[(36 + kz) * 64 + ln] =
          *(const short8*)(ws + WS_Z0 + ((size_t)(m * 4 + kz) * 64 + ln) * 16);
    }
    __syncthreads();

    // ---- ys[tt-1] = (h_{tt-1} @ Wout^T + b_out) * mask  (WGs u<8, split-K over waves) ----
    if (u < 8 && tt >= 1) {
      f32x4 yacc = {0.f, 0.f, 0.f, 0.f};
      const char* wob = woutf + ((size_t)(u * 32 + w * 4) * 64 + lane) * 16;
      #pragma unroll
      for (int i = 0; i < 4; i++) {
        const short8 bf = *(const short8*)(wob + (size_t)i * 1024);
        const short8 af = a_lds[(w * 4 + i) * 64 + lane];
        yacc = __builtin_amdgcn_mfma_f32_16x16x32_bf16(af, bf, yacc, 0, 0, 0);
      }
      {
        const int o = lane & 15, bq = (lane >> 4) * 4;
        *(f32x4*)&ysred[(w * 16 + o) * 20 + bq] = yacc;
      }
      __syncthreads();
      if (tid < 256) {
        const int o = tid & 15, b = tid >> 4;
        float s = 0.f;
        #pragma unroll
        for (int q = 0; q < 8; q++) s += ysred[(q * 16 + o) * 20 + b];
        s += b_out[u * 16 + o];
        const float val = ((tt - 1) < seq_lds[b]) ? s : 0.0f;
        out[((size_t)(m * 16 + b) * Tn + (tt - 1)) * 128 + u * 16 + o] = val;
      }
    }

    // ---- gates + state update (steps 0..T-1) ----
    if (tt < Tn) {
      const float bias_v = bias_lds[w * 16 + (lane & 15)];
      f32x4 acc0 = {bias_v, bias_v, bias_v, bias_v};
      f32x4 acc1 = {0.f, 0.f, 0.f, 0.f};
      #pragma unroll
      for (int kt = 0; kt < 36; kt += 2) {     // two chains for MFMA latency
        const short8 a0 = a_lds[kt * 64 + lane];
        const short8 a1 = a_lds[(kt + 1) * 64 + lane];
        acc0 = __builtin_amdgcn_mfma_f32_16x16x32_bf16(a0, bfr[kt], acc0, 0, 0, 0);
        acc1 = __builtin_amdgcn_mfma_f32_16x16x32_bf16(a1, bfr[kt + 1], acc1, 0, 0, 0);
      }
      if (tt == 0) {                           // step-0 out_t correction
        #pragma unroll
        for (int kt = 36; kt < 40; kt += 2) {
          const short8 a0 = a_lds[kt * 64 + lane];
          const short8 a1 = a_lds[(kt + 1) * 64 + lane];
          acc0 = __builtin_amdgcn_mfma_f32_16x16x32_bf16(a0, bfr[kt], acc0, 0, 0, 0);
          acc1 = __builtin_amdgcn_mfma_f32_16x16x32_bf16(a1, bfr[kt + 1], acc1, 0, 0, 0);
        }
      }
      {
        const int r = w * 16 + (lane & 15);
        const int bq = (lane >> 4) * 4;
        f32x4 s;
        s[0] = acc0[0] + acc1[0]; s[1] = acc0[1] + acc1[1];
        s[2] = acc0[2] + acc1[2]; s[3] = acc0[3] + acc1[3];
        *(f32x4*)&gates_lds[r * 20 + bq] = s;
      }
      __syncthreads();
      {
        const float Gi = gates_lds[(0 * 32 + jj_loc) * 20 + b_loc];
        const float Gf = gates_lds[(1 * 32 + jj_loc) * 20 + b_loc];
        const float Gg = gates_lds[(2 * 32 + jj_loc) * 20 + b_loc];
        const float Go = gates_lds[(3 * 32 + jj_loc) * 20 + b_loc];
        const float ig = fast_sig(Gi), fg = fast_sig(Gf);
        const float gg = fast_tanh(Gg), og = fast_sig(Go);
        c_reg = fg * c_reg + ig * gg;
        const float h = og * fast_tanh(c_reg);
        ((short*)htile)[(b_loc + 16 * (jj_loc >> 3)) * 8 + (jj_loc & 7)] = (short)f2bf(h);
      }
      __syncthreads();
      if (tid < 64) {                          // wave0 publishes h tile + flag
        const short8 v = htile[lane];
        *(short8*)(hbuf + (size_t)((tt & 1) * 8 + m) * 32768 + (size_t)u * 1024 +
                   (size_t)lane * 16) = v;
        __threadfence();                       // release
        if (tid == 0)
          __hip_atomic_fetch_add(&cnt[tt * 8 + m], 1, __ATOMIC_RELEASE,
                                 __HIP_MEMORY_SCOPE_AGENT);
      }
    }
  }
}

extern "C" void kernel_launch(void* const* d_in, const int* in_sizes, int n_in,
                              void* d_out, int out_size, void* d_ws, size_t ws_size,
                              hipStream_t stream) {
  (void)in_sizes; (void)n_in; (void)out_size; (void)ws_size;
  const float* x    = (const float*)d_in[0];
  const int*   seq  = (const int*)d_in[1];
  const float* hn   = (const float*)d_in[2];
  const float* cn   = (const float*)d_in[3];
  const float* outt = (const float*)d_in[4];
  const float* Wih  = (const float*)d_in[5];
  const float* Whh  = (const float*)d_in[6];
  const float* bih  = (const float*)d_in[7];
  const float* bhh  = (const float*)d_in[8];
  const float* Wout = (const float*)d_in[9];
  const float* bout = (const float*)d_in[10];
  float* out = (float*)d_out;
  char* ws = (char*)d_ws;

  hipLaunchKernelGGL(k_wfrag, dim3(32, 8, 40), dim3(64), 0, stream, Wih, Whh, Wout, ws);
  hipLaunchKernelGGL(k_misc, dim3(616), dim3(64), 0, stream, Wout, hn, outt, bout,
                     bih, bhh, Wih, ws);
  void* args[] = {(void*)&x, (void*)&seq, (void*)&cn, (void*)&bout, (void*)&out, (void*)&ws};
  hipLaunchCooperativeKernel((const void*)k_main, dim3(256), dim3(512), args, 0, stream);
}

// Round 2
// 3817.206 us; speedup vs baseline: 10.5314x; 10.5314x over previous
//
#include <hip/hip_runtime.h>
#include <stdint.h>

// AutoRegressiveLSTM: B=128, T=1024, I=128, H=1024, O=128. 4H=4096, K=I+H (+O fused)
#define Tn 1024
#define In 128

typedef __attribute__((ext_vector_type(8))) short short8;
typedef __attribute__((ext_vector_type(4))) float f32x4;
typedef unsigned long long u64;

// ---- workspace layout (bytes) ----
#define WS_WFRAG  0ull                         // 32u*8nt*40kt*64lane*16B = 10,485,760
#define WS_WOUT   (WS_WFRAG + 10485760ull)     // 8u*32kt*1024B = 262,144
#define WS_Z0     (WS_WOUT + 262144ull)        // 8m*4kt*1024B = 32,768
#define WS_HBUF   (WS_Z0 + 32768ull)           // 2buf*8m*32kt*1024B = 524,288
#define WS_BIAS   (WS_HBUF + 524288ull)        // 4096*4
#define WS_CNT    (WS_BIAS + 16384ull)         // 1024*8*4
// total ~11.35 MB

__device__ __forceinline__ unsigned short f2bf(float f) {
  unsigned u = __builtin_bit_cast(unsigned, f);
  return (unsigned short)((u + 0x7FFFu + ((u >> 16) & 1u)) >> 16);  // RNE
}
__device__ __forceinline__ float fast_sig(float v) {
  float e = __builtin_amdgcn_exp2f(-1.44269504089f * v);
  return __builtin_amdgcn_rcpf(1.0f + e);
}
__device__ __forceinline__ float fast_tanh(float v) {
  float a = fabsf(v);
  float e = __builtin_amdgcn_exp2f(-2.88539008178f * a);
  float r = (1.0f - e) * __builtin_amdgcn_rcpf(1.0f + e);
  return copysignf(r, v);
}

// ---------------------------------------------------------------------------
// K1: fused weights -> bf16 B-fragments.
// wfrag[u][nt][kt][lane][8]: B[k][col] for rows n(r)=g*1024+u*32+(r&31), r=nt*16+col.
//   kt 0..31  : W_comb_h[n][k] = W_hh[n][k] + sum_o W_ih[n][128+o]*W_out[o][k]
//   kt 32..35 : W_ih[n][k]           (x part)
//   kt 36..39 : W_ih[n][128+o]       (z0 correction part, used only at t=0)
// ---------------------------------------------------------------------------
__global__ void k_wfrag(const float* __restrict__ Wih, const float* __restrict__ Whh,
                        const float* __restrict__ Wout, char* __restrict__ ws) {
  const int u = blockIdx.x, nt = blockIdx.y, kt = blockIdx.z;
  const int lane = threadIdx.x;
  const int col = lane & 15, quad = lane >> 4;
  const int r = nt * 16 + col;
  const int g = r >> 5, jj = r & 31;
  const int n = g * 1024 + u * 32 + jj;
  float v[8];
  if (kt < 32) {
    const int k = kt * 32 + quad * 8;
    #pragma unroll
    for (int e = 0; e < 8; e++) v[e] = Whh[(size_t)n * 1024 + k + e];
    const float* wo = Wih + (size_t)n * 256 + 128;
    for (int o = 0; o < 128; o++) {
      const float wv = wo[o];
      const float* wr = Wout + (size_t)o * 1024 + k;
      #pragma unroll
      for (int e = 0; e < 8; e++) v[e] = fmaf(wv, wr[e], v[e]);
    }
  } else if (kt < 36) {
    const int k = (kt - 32) * 32 + quad * 8;
    #pragma unroll
    for (int e = 0; e < 8; e++) v[e] = Wih[(size_t)n * 256 + k + e];
  } else {
    const int o = (kt - 36) * 32 + quad * 8;
    #pragma unroll
    for (int e = 0; e < 8; e++) v[e] = Wih[(size_t)n * 256 + 128 + o + e];
  }
  short8 pk;
  #pragma unroll
  for (int e = 0; e < 8; e++) pk[e] = (short)f2bf(v[e]);
  *(short8*)(ws + WS_WFRAG + ((size_t)((u * 8 + nt) * 40 + kt) * 64 + lane) * 16) = pk;
}

// ---------------------------------------------------------------------------
// K2: misc setup (woutfrag, hn->frag into hbuf[1], z0 frag, bias2, flag zero)
// ---------------------------------------------------------------------------
__global__ void k_misc(const float* __restrict__ Wout, const float* __restrict__ hn,
                       const float* __restrict__ out_t, const float* __restrict__ bout,
                       const float* __restrict__ bih, const float* __restrict__ bhh,
                       const float* __restrict__ Wih, char* __restrict__ ws) {
  const int blk = blockIdx.x, lane = threadIdx.x;
  const int col = lane & 15, quad = lane >> 4;
  if (blk < 256) {                       // woutfrag[u][kt][lane][8] = Wout[o][j]
    const int u = blk >> 5, kt = blk & 31;
    const int o = u * 16 + col, j0 = kt * 32 + quad * 8;
    short8 pk;
    #pragma unroll
    for (int e = 0; e < 8; e++) pk[e] = (short)f2bf(Wout[(size_t)o * 1024 + j0 + e]);
    *(short8*)(ws + WS_WOUT + ((size_t)(u * 32 + kt) * 64 + lane) * 16) = pk;
  } else if (blk < 512) {                // hn -> A-frag layout into hbuf[1]
    const int t2 = blk - 256;
    const int mm = t2 >> 5, kt = t2 & 31;
    const int b = mm * 16 + col, j0 = kt * 32 + quad * 8;
    short8 pk;
    #pragma unroll
    for (int e = 0; e < 8; e++) pk[e] = (short)f2bf(hn[(size_t)b * 1024 + j0 + e]);
    *(short8*)(ws + WS_HBUF + ((size_t)((8 + mm) * 32 + kt) * 64 + lane) * 16) = pk;
  } else if (blk < 544) {                // z0 = output_t - b_out - hn@Wout^T (A-frag bf16)
    const int t2 = blk - 512;
    const int mm = t2 >> 2, kz = t2 & 3;
    const int b = mm * 16 + col;
    const int o0 = kz * 32 + quad * 8;
    float acc[8];
    #pragma unroll
    for (int e = 0; e < 8; e++) acc[e] = out_t[(size_t)b * 128 + o0 + e] - bout[o0 + e];
    for (int j = 0; j < 1024; j += 4) {
      const f32x4 h4 = *(const f32x4*)(hn + (size_t)b * 1024 + j);
      #pragma unroll
      for (int e = 0; e < 8; e++) {
        const f32x4 w4 = *(const f32x4*)(Wout + (size_t)(o0 + e) * 1024 + j);
        acc[e] -= h4[0] * w4[0] + h4[1] * w4[1] + h4[2] * w4[2] + h4[3] * w4[3];
      }
    }
    short8 pk;
    #pragma unroll
    for (int e = 0; e < 8; e++) pk[e] = (short)f2bf(acc[e]);
    *(short8*)(ws + WS_Z0 + ((size_t)(mm * 4 + kz) * 64 + lane) * 16) = pk;
  } else if (blk < 608) {                // bias2[n] = b_ih + b_hh + W_ihO @ b_out
    const int n = (blk - 544) * 64 + lane;
    float v = bih[n] + bhh[n];
    const float* wo = Wih + (size_t)n * 256 + 128;
    for (int o = 0; o < 128; o++) v = fmaf(wo[o], bout[o], v);
    ((float*)(ws + WS_BIAS))[n] = v;
  } else {                               // zero flag counters (8192 ints)
    int* c = (int*)(ws + WS_CNT);
    const int base = ((blk - 608) * 64 + lane) * 16;
    #pragma unroll
    for (int k = 0; k < 16; k++) c[base + k] = 0;
  }
}

// ---------------------------------------------------------------------------
// Main persistent kernel: 256 WGs x 512 thr. WG wg: m = wg&7 (batch group of 16),
// u = wg>>3 (units j in [32u,32u+32)). Flag sync via relaxed SYSTEM-scope atomics
// (sc0 sc1 -> MALL, the cross-XCD coherence point). No bulk cache fences.
// ---------------------------------------------------------------------------
__launch_bounds__(512, 2)
__global__ void k_main(const float* __restrict__ x, const int* __restrict__ seq,
                       const float* __restrict__ cn, const float* __restrict__ b_out,
                       float* __restrict__ out, char* __restrict__ ws) {
  __shared__ short8 a_lds[40 * 64];        // A fragments: 32 h + 4 x + 4 z0 (40 KB)
  __shared__ float  gates_lds[128 * 20];   // [row r][batch b], stride 20 (aligned+pad)
  __shared__ short8 htile[64];             // new h tile (16b x 32j) in frag order
  __shared__ float  ysred[8 * 16 * 20];    // ys split-K partials [q][o][b]
  __shared__ float  bias_lds[128];
  __shared__ int    seq_lds[16];

  const int tid  = threadIdx.x;
  const int lane = tid & 63;
  const int w    = tid >> 6;               // wave id 0..7 (= gate N-tile)
  const int wg   = blockIdx.x;
  const int m    = wg & 7, u = wg >> 3;

  const char* wfrag = ws + WS_WFRAG;
  const char* woutf = ws + WS_WOUT;
  char* hbuf  = ws + WS_HBUF;
  const float* bias2 = (const float*)(ws + WS_BIAS);
  int* cnt = (int*)(ws + WS_CNT);

  // persistent weight B-fragments in VGPRs/AGPRs: 40 x 16B = 160 regs
  short8 bfr[40];
  {
    const char* base = wfrag + ((size_t)(u * 8 + w) * 40 * 64) * 16 + (size_t)lane * 16;
    #pragma unroll
    for (int kt = 0; kt < 40; kt++) bfr[kt] = *(const short8*)(base + (size_t)kt * 1024);
  }
  if (tid < 16) seq_lds[tid] = seq[m * 16 + tid];
  if (tid < 128) {
    const int g = tid >> 5, jj = tid & 31;
    bias_lds[tid] = bias2[g * 1024 + u * 32 + jj];
  }
  const int b_loc  = tid & 15;   // batch within group
  const int jj_loc = tid >> 4;   // unit within WG (0..31)
  float c_reg = cn[(size_t)(m * 16 + b_loc) * 1024 + u * 32 + jj_loc];
  __syncthreads();

  #pragma unroll 1
  for (int tt = 0; tt <= Tn; tt++) {
    // ---- stage x_t (masked, bf16, frag layout) -- no h dependency, overlaps spin ----
    if (tt < Tn && tid < 256) {
      const int kt4 = tid >> 6, ln = tid & 63;
      const int b = ln & 15, quad = ln >> 4;
      const int i0 = kt4 * 32 + quad * 8;
      const float* xp = x + ((size_t)(m * 16 + b) * Tn + tt) * In + i0;
      const float mk = (tt < seq_lds[b]) ? 1.0f : 0.0f;
      const f32x4 x0 = *(const f32x4*)xp;
      const f32x4 x1 = *(const f32x4*)(xp + 4);
      short8 pk;
      pk[0] = (short)f2bf(x0[0] * mk); pk[1] = (short)f2bf(x0[1] * mk);
      pk[2] = (short)f2bf(x0[2] * mk); pk[3] = (short)f2bf(x0[3] * mk);
      pk[4] = (short)f2bf(x1[0] * mk); pk[5] = (short)f2bf(x1[1] * mk);
      pk[6] = (short)f2bf(x1[2] * mk); pk[7] = (short)f2bf(x1[3] * mk);
      a_lds[(32 + kt4) * 64 + ln] = pk;
    }
    // ---- stage z0 correction frags (t=0 only) ----
    if (tt == 0 && tid < 256) {
      const int kz = tid >> 6, ln = tid & 63;
      a_lds[(36 + kz) * 64 + ln] =
          *(const short8*)(ws + WS_Z0 + ((size_t)(m * 4 + kz) * 64 + ln) * 16);
    }
    // ---- wait for all 32 producers of h_{tt-1} in this batch group ----
    if (tt >= 1 && tid == 0) {
      while (__hip_atomic_load(&cnt[(tt - 1) * 8 + m], __ATOMIC_RELAXED,
                               __HIP_MEMORY_SCOPE_SYSTEM) < 32) {}
    }
    __syncthreads();
    // ---- stage h_{tt-1} (32 KB) into LDS via MALL-bypass loads ----
    {
      const u64* src = (const u64*)(hbuf + (size_t)((((tt + 1) & 1) * 8) + m) * 32768);
      u64 tmp[8];
      #pragma unroll
      for (int s = 0; s < 8; s++)
        tmp[s] = __hip_atomic_load(&src[s * 512 + tid], __ATOMIC_RELAXED,
                                   __HIP_MEMORY_SCOPE_SYSTEM);
      u64* dst = (u64*)a_lds;
      #pragma unroll
      for (int s = 0; s < 8; s++) dst[s * 512 + tid] = tmp[s];
    }
    __syncthreads();

    // ---- gates + state update (steps 0..T-1) ----
    if (tt < Tn) {
      const float bias_v = bias_lds[w * 16 + (lane & 15)];
      f32x4 acc0 = {bias_v, bias_v, bias_v, bias_v};
      f32x4 acc1 = {0.f, 0.f, 0.f, 0.f};
      #pragma unroll
      for (int kt = 0; kt < 36; kt += 2) {     // two chains for MFMA latency
        const short8 a0 = a_lds[kt * 64 + lane];
        const short8 a1 = a_lds[(kt + 1) * 64 + lane];
        acc0 = __builtin_amdgcn_mfma_f32_16x16x32_bf16(a0, bfr[kt], acc0, 0, 0, 0);
        acc1 = __builtin_amdgcn_mfma_f32_16x16x32_bf16(a1, bfr[kt + 1], acc1, 0, 0, 0);
      }
      if (tt == 0) {                           // step-0 out_t correction
        #pragma unroll
        for (int kt = 36; kt < 40; kt += 2) {
          const short8 a0 = a_lds[kt * 64 + lane];
          const short8 a1 = a_lds[(kt + 1) * 64 + lane];
          acc0 = __builtin_amdgcn_mfma_f32_16x16x32_bf16(a0, bfr[kt], acc0, 0, 0, 0);
          acc1 = __builtin_amdgcn_mfma_f32_16x16x32_bf16(a1, bfr[kt + 1], acc1, 0, 0, 0);
        }
      }
      {
        const int r = w * 16 + (lane & 15);
        const int bq = (lane >> 4) * 4;
        f32x4 s;
        s[0] = acc0[0] + acc1[0]; s[1] = acc0[1] + acc1[1];
        s[2] = acc0[2] + acc1[2]; s[3] = acc0[3] + acc1[3];
        *(f32x4*)&gates_lds[r * 20 + bq] = s;
      }
      __syncthreads();
      {
        const float Gi = gates_lds[(0 * 32 + jj_loc) * 20 + b_loc];
        const float Gf = gates_lds[(1 * 32 + jj_loc) * 20 + b_loc];
        const float Gg = gates_lds[(2 * 32 + jj_loc) * 20 + b_loc];
        const float Go = gates_lds[(3 * 32 + jj_loc) * 20 + b_loc];
        const float ig = fast_sig(Gi), fg = fast_sig(Gf);
        const float gg = fast_tanh(Gg), og = fast_sig(Go);
        c_reg = fg * c_reg + ig * gg;
        const float h = og * fast_tanh(c_reg);
        ((short*)htile)[(b_loc + 16 * (jj_loc >> 3)) * 8 + (jj_loc & 7)] = (short)f2bf(h);
      }
      __syncthreads();
      if (tid < 64) {                          // wave0 publishes h tile + flag (ASAP)
        const short8 v = htile[lane];
        u64* dstp = (u64*)(hbuf + (size_t)((tt & 1) * 8 + m) * 32768 +
                           (size_t)u * 1024) + (size_t)lane * 2;
        const u64* pv = (const u64*)&v;
        __hip_atomic_store(&dstp[0], pv[0], __ATOMIC_RELAXED, __HIP_MEMORY_SCOPE_SYSTEM);
        __hip_atomic_store(&dstp[1], pv[1], __ATOMIC_RELAXED, __HIP_MEMORY_SCOPE_SYSTEM);
        asm volatile("s_waitcnt vmcnt(0)" ::: "memory");   // stores visible at MALL
        if (tid == 0)
          __hip_atomic_fetch_add(&cnt[tt * 8 + m], 1, __ATOMIC_RELAXED,
                                 __HIP_MEMORY_SCOPE_SYSTEM);
      }
    }

    // ---- ys[tt-1] = (h_{tt-1} @ Wout^T + b_out) * mask -- off critical path ----
    if (u < 8 && tt >= 1) {
      f32x4 yacc = {0.f, 0.f, 0.f, 0.f};
      const char* wob = woutf + ((size_t)(u * 32 + w * 4) * 64 + lane) * 16;
      #pragma unroll
      for (int i = 0; i < 4; i++) {
        const short8 bf = *(const short8*)(wob + (size_t)i * 1024);
        const short8 af = a_lds[(w * 4 + i) * 64 + lane];
        yacc = __builtin_amdgcn_mfma_f32_16x16x32_bf16(af, bf, yacc, 0, 0, 0);
      }
      {
        const int o = lane & 15, bq = (lane >> 4) * 4;
        *(f32x4*)&ysred[(w * 16 + o) * 20 + bq] = yacc;
      }
      __syncthreads();
      if (tid < 256) {
        const int o = tid & 15, b = tid >> 4;
        float s = 0.f;
        #pragma unroll
        for (int q = 0; q < 8; q++) s += ysred[(q * 16 + o) * 20 + b];
        s += b_out[u * 16 + o];
        const float val = ((tt - 1) < seq_lds[b]) ? s : 0.0f;
        out[((size_t)(m * 16 + b) * Tn + (tt - 1)) * 128 + u * 16 + o] = val;
      }
      __syncthreads();
    }
  }
}

extern "C" void kernel_launch(void* const* d_in, const int* in_sizes, int n_in,
                              void* d_out, int out_size, void* d_ws, size_t ws_size,
                              hipStream_t stream) {
  (void)in_sizes; (void)n_in; (void)out_size; (void)ws_size;
  const float* x    = (const float*)d_in[0];
  const int*   seq  = (const int*)d_in[1];
  const float* hn   = (const float*)d_in[2];
  const float* cn   = (const float*)d_in[3];
  const float* outt = (const float*)d_in[4];
  const float* Wih  = (const float*)d_in[5];
  const float* Whh  = (const float*)d_in[6];
  const float* bih  = (const float*)d_in[7];
  const float* bhh  = (const float*)d_in[8];
  const float* Wout = (const float*)d_in[9];
  const float* bout = (const float*)d_in[10];
  float* out = (float*)d_out;
  char* ws = (char*)d_ws;

  hipLaunchKernelGGL(k_wfrag, dim3(32, 8, 40), dim3(64), 0, stream, Wih, Whh, Wout, ws);
  hipLaunchKernelGGL(k_misc, dim3(616), dim3(64), 0, stream, Wout, hn, outt, bout,
                     bih, bhh, Wih, ws);
  void* args[] = {(void*)&x, (void*)&seq, (void*)&cn, (void*)&bout, (void*)&out, (void*)&ws};
  hipLaunchCooperativeKernel((const void*)k_main, dim3(256), dim3(512), args, 0, stream);
}